// Round 10
// baseline (158.564 us; speedup 1.0000x reference)
//
#include <hip/hip_runtime.h>
#include <stdint.h>

// MPS chain contraction, B=32768, L=256, D=16.
// R17: R12's source-order next-chunk prefetch (the only lookahead form the
//   compiler has provably kept resident: R12 VGPR=56 -> 58.8us) combined
//   with R16's direct float2 coefficients (no bpermute) and 4 waves/SIMD
//   (1024 blocks x 1 chain/wave). Ledger: demand loads = 72-74us at any
//   occupancy; 1-chunk lookahead @ 2 waves/SIMD = 58.8; pipe floor ~21us
//   -> residual is both-pipes-idle L2 latency when both resident waves
//   wait. 4 independent waves x 1 chunk lookahead should tile the stalls.
//   No asm, no sched_barrier, no setprio, no carousel (R8/13/14/15 lesson).

typedef short  bf16x8 __attribute__((ext_vector_type(8)));
typedef float  f32x4  __attribute__((ext_vector_type(4)));
typedef int    i32x4  __attribute__((ext_vector_type(4)));
typedef unsigned int u32;

#define NPF 64
#define NPB 63
#define BWD_OFF (NPF*4*64)   // i32x4 units

#define PACK_HI(hi, lo) ((int)__builtin_amdgcn_perm((u32)(hi), (u32)(lo), 0x07060302u))

__device__ __forceinline__ u32 rne_bump(u32 u){ return u + 0x7FFFu + ((u >> 16) & 1u); }

// Pair-fragment table: blocks 0..63 fwd (j=bid), 64..126 bwd (j=bid-64).
// fwd: G[m][cq] = sum_r Ca[cq][p][r]*Cb[r][q][m],  Ca=cm[2j], Cb=cm[2j+1]
// bwd: G[m][cq] = sum_r Ca[m][p][r]*Cb[r][q][cq],  Ca=cm[252-2j], Cb=cm[253-2j]
// lane (m=lane&15, g=lane>>4) packs cols 4g..4g+3 hi (dw0,1) and lo (dw2,3).
__global__ void build_pair_frags(const float* __restrict__ cm, i32x4* __restrict__ ws)
{
  __shared__ float Ca[512], Cb[512];   // [x][p][y] = cm[t][x][p][y]
  const int bid = blockIdx.x;
  const bool fwd = bid < NPF;
  const int j  = fwd ? bid : bid - NPF;
  const int ta = fwd ? 2*j     : 252 - 2*j;
  const int tb = fwd ? 2*j + 1 : 253 - 2*j;
  {
    const float* A = cm + ta*512;
    const float* B = cm + tb*512;
    for (int i = threadIdx.x; i < 512; i += 256){ Ca[i] = A[i]; Cb[i] = B[i]; }
  }
  __syncthreads();
  const int f    = threadIdx.x >> 6;    // combo p*2+q
  const int lane = threadIdx.x & 63;
  const int m    = lane & 15;
  const int g    = lane >> 4;
  const int p    = f >> 1, q = f & 1;
  u32 hi[4], lo[4];
  #pragma unroll
  for (int x = 0; x < 4; ++x){
    const int cq = 4*g + x;
    float acc = 0.f;
    #pragma unroll
    for (int r = 0; r < 16; ++r){
      const float a = fwd ? Ca[cq*32 + p*16 + r] : Ca[m*32 + p*16 + r];
      const float b = fwd ? Cb[r*32 + q*16 + m]  : Cb[r*32 + q*16 + cq];
      acc = fmaf(a, b, acc);
    }
    const u32 u  = __float_as_uint(acc);
    const u32 aa = rne_bump(u);
    const float hf = __uint_as_float(aa & 0xFFFF0000u);
    const u32 bb = rne_bump(__float_as_uint(acc - hf));
    hi[x] = aa >> 16; lo[x] = bb >> 16;
  }
  i32x4 w;
  w[0] = (int)(hi[0] | (hi[1] << 16));
  w[1] = (int)(hi[2] | (hi[3] << 16));
  w[2] = (int)(lo[0] | (lo[1] << 16));
  w[3] = (int)(lo[2] | (lo[3] << 16));
  ws[(fwd ? 0 : BWD_OFF) + (j*4 + f)*64 + lane] = w;
}

__device__ __forceinline__ void make_bfrag(const float (&v)[4], i32x4 &bfr)
{
  const u32 u0 = __float_as_uint(v[0]), u1 = __float_as_uint(v[1]);
  const u32 u2 = __float_as_uint(v[2]), u3 = __float_as_uint(v[3]);
  const float l0 = v[0] - __uint_as_float(u0 & 0xFFFF0000u);
  const float l1 = v[1] - __uint_as_float(u1 & 0xFFFF0000u);
  const float l2 = v[2] - __uint_as_float(u2 & 0xFFFF0000u);
  const float l3 = v[3] - __uint_as_float(u3 & 0xFFFF0000u);
  bfr[0] = PACK_HI(u1, u0);
  bfr[1] = PACK_HI(u3, u2);
  bfr[2] = PACK_HI(__float_as_uint(l1), __float_as_uint(l0));
  bfr[3] = PACK_HI(__float_as_uint(l3), __float_as_uint(l2));
}

__device__ __forceinline__ void pair_step(
    const i32x4 &G0, const i32x4 &G1, const i32x4 &G2, const i32x4 &G3,
    float2 cA, float2 cB, float (&v)[4], i32x4 &bfr)
{
  const float c00 = cA.x*cB.x, c01 = cA.x*cB.y;
  const float c10 = cA.y*cB.x, c11 = cA.y*cB.y;
  i32x4 sw; sw[0]=bfr[2]; sw[1]=bfr[3]; sw[2]=bfr[0]; sw[3]=bfr[1];
  const bf16x8 bh = __builtin_bit_cast(bf16x8, bfr);
  const bf16x8 bs = __builtin_bit_cast(bf16x8, sw);
  const f32x4 z = {0.f,0.f,0.f,0.f};
  f32x4 a00 = __builtin_amdgcn_mfma_f32_16x16x32_bf16(__builtin_bit_cast(bf16x8,G0), bh, z, 0,0,0);
  a00 = __builtin_amdgcn_mfma_f32_16x16x32_bf16(__builtin_bit_cast(bf16x8,G0), bs, a00, 0,0,0);
  f32x4 a01 = __builtin_amdgcn_mfma_f32_16x16x32_bf16(__builtin_bit_cast(bf16x8,G1), bh, z, 0,0,0);
  a01 = __builtin_amdgcn_mfma_f32_16x16x32_bf16(__builtin_bit_cast(bf16x8,G1), bs, a01, 0,0,0);
  f32x4 a10 = __builtin_amdgcn_mfma_f32_16x16x32_bf16(__builtin_bit_cast(bf16x8,G2), bh, z, 0,0,0);
  a10 = __builtin_amdgcn_mfma_f32_16x16x32_bf16(__builtin_bit_cast(bf16x8,G2), bs, a10, 0,0,0);
  f32x4 a11 = __builtin_amdgcn_mfma_f32_16x16x32_bf16(__builtin_bit_cast(bf16x8,G3), bh, z, 0,0,0);
  a11 = __builtin_amdgcn_mfma_f32_16x16x32_bf16(__builtin_bit_cast(bf16x8,G3), bs, a11, 0,0,0);
  #pragma unroll
  for (int i2 = 0; i2 < 4; ++i2)
    v[i2] = c00*a00[i2] + c01*a01[i2] + c10*a10[i2] + c11*a11[i2];
  make_bfrag(v, bfr);
}

__global__ __launch_bounds__(256, 4) void mps_chain(
  const float* __restrict__ phi,
  const float* __restrict__ core_first,
  const float* __restrict__ core_last,
  const float* __restrict__ bias,
  const i32x4* __restrict__ ws,
  float* __restrict__ out)
{
  const int lane = threadIdx.x & 63;
  const int wv   = threadIdx.x >> 6;
  const int b0   = blockIdx.x * 32;
  const int n    = lane & 15;            // sample column
  const int g    = lane >> 4;            // matrix row group
  const int half = wv & 1;
  const int s_in = half*16 + n;
  const bool isFwd = (wv < 2);
  const int dirIdx = isFwd ? 0 : 1;

  __shared__ float red[64*20];           // epilogue reduction only (5 KB)

  const i32x4* wsD    = isFwd ? ws : (ws + BWD_OFF);
  const int    maxPr  = isFwd ? NPF - 1 : NPB - 1;
  const i32x4* wsLane = wsD + lane;      // + pr*256 + f*64 selects (pair, combo)

  // own sample row; float2 index i = phi site i (feat0, feat1)
  const float*  row = phi + (size_t)(b0 + s_in) * 512;
  const float2* c2  = (const float2*)row;

  // chunk-c coefficient sites (verified by R15/R16 passes):
  //   even pair 2c:   sites uB+st*c, uB+st*c+1
  //   odd  pair 2c+1: sites vB+st*c, vB+st*c+1
  const int uB = isFwd ? 1 : 253;
  const int vB = isFwd ? 3 : 251;
  const int st = isFwd ? 4 : -4;

  // ---- chain state ----
  float v[4];
  i32x4 bfr;
  {
    if (isFwd){
      const float2 p0 = *(const float2*)row;
      #pragma unroll
      for (int r = 0; r < 4; ++r){
        const int rr = g*4 + r;
        v[r] = p0.x * core_first[rr] + p0.y * core_first[16 + rr];
      }
    } else {
      const float2 pL = *(const float2*)(row + 510);
      #pragma unroll
      for (int r = 0; r < 4; ++r){
        const int rr = g*4 + r;
        v[r] = pL.x * core_last[2*rr] + pL.y * core_last[2*rr + 1];
      }
    }
    make_bfrag(v, bfr);
  }

  // ---- prefetch state: current chunk's pairs + coefficients (R12 pattern) ----
  i32x4 A0,A1,A2,A3, B0,B1,B2,B3;
  float2 eA, eB, oA, oB;

  { const i32x4* s = wsLane;        A0=s[0]; A1=s[64]; A2=s[128]; A3=s[192]; }
  { const i32x4* s = wsLane + 256;  B0=s[0]; B1=s[64]; B2=s[128]; B3=s[192]; }
  eA = c2[uB];     eB = c2[uB + 1];
  oA = c2[vB];     oB = c2[vB + 1];

  #pragma unroll 1
  for (int c = 0; c < 31; ++c){
    // ---- compute even pair 2c, then issue its replacement (2c+2) ----
    pair_step(A0,A1,A2,A3, eA,eB, v, bfr);
    { const i32x4* s = wsLane + (2*c + 2)*256;               // <= 62, in range
      A0=s[0]; A1=s[64]; A2=s[128]; A3=s[192]; }

    // ---- compute odd pair 2c+1, then issue its replacement (2c+3) ----
    pair_step(B0,B1,B2,B3, oA,oB, v, bfr);
    { int j3 = 2*c + 3; if (j3 > maxPr) j3 = maxPr;          // bwd c=30: 63->62
      const i32x4* s = wsLane + j3*256;
      B0=s[0]; B1=s[64]; B2=s[128]; B3=s[192]; }

    // ---- next chunk's coefficients ----
    const int u1 = uB + st*(c+1), w1 = vB + st*(c+1);
    eA = c2[u1]; eB = c2[u1+1];
    oA = c2[w1]; oB = c2[w1+1];
  }

  // ---- peeled chunk 31: pair 62 always; pair 63 fwd only ----
  pair_step(A0,A1,A2,A3, eA,eB, v, bfr);
  if (isFwd)
    pair_step(B0,B1,B2,B3, oA,oB, v, bfr);

  // ---- epilogue: cross-wave reduction ----
  *(float4*)&red[(dirIdx*32 + s_in)*20 + 4*g] =
      make_float4(v[0], v[1], v[2], v[3]);
  __syncthreads();
  if (threadIdx.x < 32){
    const int s = threadIdx.x;
    float acc = bias[0];
    #pragma unroll
    for (int qq = 0; qq < 16; ++qq)
      acc += red[s*20 + qq] * red[(32 + s)*20 + qq];
    out[b0 + s] = acc;
  }
}

extern "C" void kernel_launch(void* const* d_in, const int* in_sizes, int n_in,
                              void* d_out, int out_size, void* d_ws, size_t ws_size,
                              hipStream_t stream)
{
  const float* phi  = (const float*)d_in[0];  // [32768,256,2]
  const float* cf   = (const float*)d_in[1];  // [2,16]
  const float* cm   = (const float*)d_in[2];  // [254,16,2,16]
  const float* cl   = (const float*)d_in[3];  // [16,2]
  const float* bias = (const float*)d_in[4];  // scalar
  i32x4* ws = (i32x4*)d_ws;                   // (64+63)*4*64*16B = 508 KB

  build_pair_frags<<<NPF + NPB, 256, 0, stream>>>(cm, ws);
  mps_chain<<<1024, 256, 0, stream>>>(phi, cf, cl, bias, ws, (float*)d_out);
}